// Round 2
// baseline (384.461 us; speedup 1.0000x reference)
//
#include <hip/hip_runtime.h>
#include <hip/hip_bf16.h>
#include <cstdint>

#define NN   8192
#define HID  128

typedef __attribute__((ext_vector_type(8)))  __bf16          bf16x8;
typedef __attribute__((ext_vector_type(16))) float           f32x16;
typedef __attribute__((ext_vector_type(8)))  unsigned short  u16x8;
typedef __attribute__((ext_vector_type(4)))  unsigned short  u16x4;
typedef __attribute__((ext_vector_type(4)))  float           f32x4;

__device__ __forceinline__ float b2f(unsigned short u){
  union { unsigned int i; float f; } v; v.i = ((unsigned int)u) << 16; return v.f;
}
__device__ __forceinline__ unsigned short f2b(float f){
  unsigned int i = __float_as_uint(f);
  unsigned int r = (i + 0x7FFFu + ((i >> 16) & 1u)) >> 16;   // RNE
  return (unsigned short)r;
}
__device__ __forceinline__ void gld_lds16(const void* g, void* l){
  __builtin_amdgcn_global_load_lds((const __attribute__((address_space(1))) unsigned int*)g,
                                   (__attribute__((address_space(3))) unsigned int*)l, 16, 0, 0);
}

// ---------------- dtype detect: bf16 buffers -> flag=1, f32 -> flag=0 ----------------
__global__ __launch_bounds__(256) void k_detect(const unsigned int* __restrict__ a,
                                                int* __restrict__ flag){
  __shared__ int cnt;
  if(threadIdx.x == 0) cnt = 0;
  __syncthreads();
  int c = 0;
  #pragma unroll
  for(int i = 0; i < 16; ++i){
    unsigned int w = a[i * 256 + threadIdx.x];
    c += (((w >> 8) & 0xC0u) == 0u) ? 1 : 0;   // byte1: bf16 high-byte vs f32 mantissa byte
  }
  atomicAdd(&cnt, c);
  __syncthreads();
  if(threadIdx.x == 0) *flag = (cnt > 3000) ? 1 : 0;
}

// ---------------- deg + inv_sqrt_deg: one wave per row ----------------
__global__ __launch_bounds__(256) void k_deg(const void* __restrict__ adjv,
                                             const int* __restrict__ flagp,
                                             float* __restrict__ isd){
  const int wid = threadIdx.x >> 6, l = threadIdx.x & 63;
  const int row = blockIdx.x * 4 + wid;
  float s = 0.f;
  if(*flagp){
    const u16x8* rp = (const u16x8*)((const unsigned short*)adjv + (size_t)row * NN);
    #pragma unroll
    for(int it = 0; it < 16; ++it){
      u16x8 v = rp[it * 64 + l];
      #pragma unroll
      for(int j = 0; j < 8; ++j) s += b2f(v[j]);
    }
  } else {
    const f32x4* rp = (const f32x4*)((const float*)adjv + (size_t)row * NN);
    #pragma unroll
    for(int it = 0; it < 32; ++it){
      f32x4 v = rp[it * 64 + l];
      s += v[0] + v[1] + v[2] + v[3];
    }
  }
  #pragma unroll
  for(int m = 32; m > 0; m >>= 1) s += __shfl_xor(s, m, 64);
  if(l == 0) isd[row] = (s > 0.f) ? rsqrtf(fmaxf(s, 1e-12f)) : 0.f;
}

// ---------------- feat0 = concat(pos, emb) as f32 ----------------
__global__ __launch_bounds__(256) void k_feat0(const void* __restrict__ pos,
                                               const void* __restrict__ emb,
                                               const int* __restrict__ flagp,
                                               float* __restrict__ feat){
  const int x = blockIdx.x * 256 + threadIdx.x;       // 1M total
  const int r = x >> 7, c = x & 127;
  float v;
  if(*flagp){
    v = b2f(c < 3 ? ((const unsigned short*)pos)[r * 3 + c]
                  : ((const unsigned short*)emb)[r * 125 + (c - 3)]);
  } else {
    v = (c < 3) ? ((const float*)pos)[r * 3 + c]
                : ((const float*)emb)[r * 125 + (c - 3)];
  }
  feat[x] = v;
}

// ---------------- W transpose to bf16: Wt[l][c][i] = bf16(Ws[l][i][c]) ----------------
__global__ __launch_bounds__(256) void k_wt(const void* __restrict__ Ws,
                                            const int* __restrict__ flagp,
                                            unsigned short* __restrict__ Wt){
  const int x = blockIdx.x * 256 + threadIdx.x;       // 65536 total
  const int lyr = x >> 14, rem = x & 16383, i = rem >> 7, c = rem & 127;
  unsigned short u;
  if(*flagp) u = ((const unsigned short*)Ws)[x];
  else       u = f2b(((const float*)Ws)[x]);
  Wt[lyr * 16384 + c * 128 + i] = u;
}

// ---------------- B_t[c][k] = bf16( (feat[k]*isd[k]) @ W )  (128-row tiles) ------
__global__ __launch_bounds__(256) void k_makeB(const float* __restrict__ feat,
                                               const float* __restrict__ isd,
                                               const unsigned short* __restrict__ Wt,
                                               unsigned short* __restrict__ Bt){
  __shared__ char lds[65536];                 // [0,32K)=A(feat bf16), [32K,64K)=Wt, reuse for bounce
  const int t = threadIdx.x, wid = t >> 6, l = t & 63;
  const int r0 = blockIdx.x * 128;

  // stage Wt (bf16, rows of 256B) via global_load_lds, pre-swizzled source
  #pragma unroll
  for(int q = 0; q < 8; ++q){
    int ob = q * 4096 + wid * 1024;           // wave-uniform LDS base
    int o  = ob + l * 16;
    int c  = o >> 8, x = o & 255;
    const char* src = (const char*)Wt + c * 256 + (x ^ ((c & 7) << 4));
    gld_lds16(src, lds + 32768 + ob);
  }
  // stage A = bf16(feat * isd), swizzled ds_write
  #pragma unroll
  for(int q = 0; q < 16; ++q){
    int idx4 = q * 256 + t;
    int r = idx4 >> 5, i4 = idx4 & 31;
    f32x4 v = ((const f32x4*)(feat + (size_t)(r0 + r) * HID))[i4];
    float sc = isd[r0 + r];
    u16x4 w;
    w[0] = f2b(v[0] * sc); w[1] = f2b(v[1] * sc);
    w[2] = f2b(v[2] * sc); w[3] = f2b(v[3] * sc);
    *(u16x4*)(lds + r * 256 + ((i4 * 8) ^ ((r & 7) << 4))) = w;
  }
  __syncthreads();

  const int wm = wid >> 1, wn = wid & 1;      // 2x2 waves, 64x64 each
  f32x16 acc[2][2];
  #pragma unroll
  for(int a = 0; a < 2; ++a)
    #pragma unroll
    for(int b = 0; b < 2; ++b)
      #pragma unroll
      for(int r2 = 0; r2 < 16; ++r2) acc[a][b][r2] = 0.f;

  const int swz = (l & 7) << 4;               // row&7 == l&7 for all frags
  #pragma unroll
  for(int st = 0; st < 8; ++st){
    int ko = (st * 32 + ((l >> 5) << 4)) ^ swz;
    bf16x8 a0 = *(const bf16x8*)(lds + (wm * 64 +      (l & 31)) * 256 + ko);
    bf16x8 a1 = *(const bf16x8*)(lds + (wm * 64 + 32 + (l & 31)) * 256 + ko);
    bf16x8 b0 = *(const bf16x8*)(lds + 32768 + (wn * 64 +      (l & 31)) * 256 + ko);
    bf16x8 b1 = *(const bf16x8*)(lds + 32768 + (wn * 64 + 32 + (l & 31)) * 256 + ko);
    acc[0][0] = __builtin_amdgcn_mfma_f32_32x32x16_bf16(a0, b0, acc[0][0], 0, 0, 0);
    acc[0][1] = __builtin_amdgcn_mfma_f32_32x32x16_bf16(a0, b1, acc[0][1], 0, 0, 0);
    acc[1][0] = __builtin_amdgcn_mfma_f32_32x32x16_bf16(a1, b0, acc[1][0], 0, 0, 0);
    acc[1][1] = __builtin_amdgcn_mfma_f32_32x32x16_bf16(a1, b1, acc[1][1], 0, 0, 0);
  }
  __syncthreads();
  // bounce transpose into [128 c][136 r] u16 (272 B rows, b128-aligned)
  #pragma unroll
  for(int mi = 0; mi < 2; ++mi)
    #pragma unroll
    for(int ni = 0; ni < 2; ++ni){
      int c = wn * 64 + ni * 32 + (l & 31);
      #pragma unroll
      for(int reg = 0; reg < 16; ++reg){
        int r = wm * 64 + mi * 32 + (reg & 3) + 8 * (reg >> 2) + 4 * (l >> 5);
        *(unsigned short*)(lds + c * 272 + r * 2) = f2b(acc[mi][ni][reg]);
      }
    }
  __syncthreads();
  // write ALL 128 r per c: 128 c x 16 chunks of 16B = 2048 chunks  (round-1 bug: was 1024)
  #pragma unroll
  for(int q = 0; q < 8; ++q){
    int id = q * 256 + t;
    int c = id >> 4, xc = id & 15;
    u16x8 v = *(const u16x8*)(lds + c * 272 + xc * 16);
    *(u16x8*)((char*)Bt + (size_t)c * (NN * 2) + (size_t)r0 * 2 + xc * 16) = v;
  }
}

// ---------------- main GEMM: partial[ks] = adj[r0:r0+64, kwin] @ h2[kwin, :] ----
__global__ __launch_bounds__(128) void k_gemm(const void* __restrict__ adjv,
                                              const unsigned short* __restrict__ Bt,
                                              const int* __restrict__ flagp,
                                              float* __restrict__ partial){
  __shared__ char lds[24576];                 // 2 bufs x (A 4KiB + B 8KiB), 64B rows
  const int t = threadIdx.x, wid = t >> 6, l = t & 63;
  const int r0 = blockIdx.x * 64;
  const int kbase = blockIdx.y * 1024;
  const int mode = *flagp;
  const unsigned short* adj_h = (const unsigned short*)adjv;
  const float*          adj_f = (const float*)adjv;

  auto stage = [&](int buf, int kt){
    const int bb = buf * 12288;
    if(mode){
      #pragma unroll
      for(int q = 0; q < 2; ++q){             // A: 64 rows x 64B, direct bf16
        int ob = q * 2048 + wid * 1024;
        int o = ob + l * 16;
        int row = o >> 6, x = o & 63;
        const char* src = (const char*)adj_h + ((size_t)(r0 + row) * NN + kt) * 2
                          + (x ^ (((row >> 1) & 3) << 4));
        gld_lds16(src, lds + bb + ob);
      }
    } else {
      #pragma unroll
      for(int q = 0; q < 4; ++q){             // A: f32 load + convert + swizzled ds_write
        int chunk = q * 128 + t;              // 512 chunks of 4 k-values
        int row = chunk >> 3, kq = chunk & 7;
        f32x4 v = *(const f32x4*)(adj_f + (size_t)(r0 + row) * NN + kt + kq * 4);
        u16x4 w;
        w[0] = f2b(v[0]); w[1] = f2b(v[1]); w[2] = f2b(v[2]); w[3] = f2b(v[3]);
        *(u16x4*)(lds + bb + row * 64 + ((kq * 8) ^ (((row >> 1) & 3) << 4))) = w;
      }
    }
    #pragma unroll
    for(int q = 0; q < 4; ++q){               // B: 128 cols x 64B (Bt is always bf16)
      int ob = q * 2048 + wid * 1024;
      int o = ob + l * 16;
      int c = o >> 6, x = o & 63;
      const char* src = (const char*)Bt + ((size_t)c * NN + kt) * 2
                        + (x ^ (((c >> 1) & 3) << 4));
      gld_lds16(src, lds + bb + 4096 + ob);
    }
  };

  f32x16 acc[2][2];
  #pragma unroll
  for(int a = 0; a < 2; ++a)
    #pragma unroll
    for(int b = 0; b < 2; ++b)
      #pragma unroll
      for(int r2 = 0; r2 < 16; ++r2) acc[a][b][r2] = 0.f;

  const int rlo = l & 31;
  const int swz = ((l >> 1) & 3) << 4;        // same for rows r, r+32, cols c, c+32

  stage(0, kbase);
  for(int it = 0; it < 32; ++it){
    const int cur = it & 1;
    __syncthreads();
    if(it < 31) stage(cur ^ 1, kbase + (it + 1) * 32);
    const int bb = cur * 12288;
    #pragma unroll
    for(int kk = 0; kk < 2; ++kk){
      int ko = (kk * 32 + ((l >> 5) << 4)) ^ swz;
      bf16x8 a0 = *(const bf16x8*)(lds + bb +        rlo       * 64 + ko);
      bf16x8 a1 = *(const bf16x8*)(lds + bb +       (rlo + 32) * 64 + ko);
      bf16x8 b0 = *(const bf16x8*)(lds + bb + 4096 + (wid * 64 + rlo)      * 64 + ko);
      bf16x8 b1 = *(const bf16x8*)(lds + bb + 4096 + (wid * 64 + rlo + 32) * 64 + ko);
      acc[0][0] = __builtin_amdgcn_mfma_f32_32x32x16_bf16(a0, b0, acc[0][0], 0, 0, 0);
      acc[0][1] = __builtin_amdgcn_mfma_f32_32x32x16_bf16(a0, b1, acc[0][1], 0, 0, 0);
      acc[1][0] = __builtin_amdgcn_mfma_f32_32x32x16_bf16(a1, b0, acc[1][0], 0, 0, 0);
      acc[1][1] = __builtin_amdgcn_mfma_f32_32x32x16_bf16(a1, b1, acc[1][1], 0, 0, 0);
    }
  }

  float* pp = partial + ((size_t)blockIdx.y << 20);
  #pragma unroll
  for(int mi = 0; mi < 2; ++mi)
    #pragma unroll
    for(int ni = 0; ni < 2; ++ni)
      #pragma unroll
      for(int reg = 0; reg < 16; ++reg){
        int r = r0 + mi * 32 + (reg & 3) + 8 * (reg >> 2) + 4 * (l >> 5);
        int c = wid * 64 + ni * 32 + (l & 31);
        pp[(size_t)r * HID + c] = acc[mi][ni][reg];
      }
}

// ---------------- reduce partials + norm + bias + softplus ----------------
template<bool LAST>
__global__ __launch_bounds__(256) void k_epi(const float* __restrict__ partial,
                                             const float* __restrict__ isd,
                                             const void* __restrict__ bsv,
                                             int lyr,
                                             const int* __restrict__ flagp,
                                             float* __restrict__ feat,
                                             void* __restrict__ out){
  const int x = blockIdx.x * 256 + threadIdx.x;
  float v = 0.f;
  #pragma unroll
  for(int p = 0; p < 8; ++p) v += partial[((size_t)p << 20) + x];
  const int r = x >> 7, c = x & 127;
  const int mode = *flagp;
  float b = mode ? b2f(((const unsigned short*)bsv)[lyr * 128 + c])
                 : ((const float*)bsv)[lyr * 128 + c];
  v = v * isd[r] + b;
  float sp = fmaxf(v, 0.f) + log1pf(expf(-fabsf(v)));   // stable softplus
  if(LAST){
    if(mode) ((unsigned short*)out)[x] = f2b(sp);
    else     ((float*)out)[x] = sp;
  } else {
    feat[x] = sp;
  }
}

extern "C" void kernel_launch(void* const* d_in, const int* in_sizes, int n_in,
                              void* d_out, int out_size, void* d_ws, size_t ws_size,
                              hipStream_t stream){
  const void* pos = d_in[0];
  const void* emb = d_in[1];
  const void* adj = d_in[2];
  const void* Ws  = d_in[3];
  const void* bs  = d_in[4];

  // ws layout (bytes): flag @0 | isd @0x1000 (32K) | feat @0x10000 (4M)
  //                    Bt @0x410000 (2M) | Wt @0x610000 (128K) | partial @0x630000 (32M)
  char* ws = (char*)d_ws;
  int*            flag    = (int*)(ws);
  float*          isd     = (float*)(ws + 0x1000);
  float*          feat    = (float*)(ws + 0x10000);
  unsigned short* Bt      = (unsigned short*)(ws + 0x410000);
  unsigned short* Wt      = (unsigned short*)(ws + 0x610000);
  float*          partial = (float*)(ws + 0x630000);

  k_detect<<<1,    256, 0, stream>>>((const unsigned int*)adj, flag);
  k_deg   <<<2048, 256, 0, stream>>>(adj, flag, isd);
  k_feat0 <<<4096, 256, 0, stream>>>(pos, emb, flag, feat);
  k_wt    <<<256,  256, 0, stream>>>(Ws, flag, Wt);
  for(int lyr = 0; lyr < 4; ++lyr){
    k_makeB<<<64, 256, 0, stream>>>(feat, isd, Wt + lyr * 16384, Bt);
    k_gemm <<<dim3(128, 8), 128, 0, stream>>>(adj, Bt, flag, partial);
    if(lyr < 3) k_epi<false><<<4096, 256, 0, stream>>>(partial, isd, bs, lyr, flag, feat, nullptr);
    else        k_epi<true ><<<4096, 256, 0, stream>>>(partial, isd, bs, lyr, flag, nullptr, d_out);
  }
}